// Round 5
// baseline (686.951 us; speedup 1.0000x reference)
//
#include <hip/hip_runtime.h>

#define Nn 100000
#define Ee 1600000
#define Pp 1000000
#define EPSf 1e-5f

typedef _Float16 f16x8 __attribute__((ext_vector_type(8)));
typedef _Float16 f16x4 __attribute__((ext_vector_type(4)));
typedef _Float16 f16x2 __attribute__((ext_vector_type(2)));
typedef float f32x4 __attribute__((ext_vector_type(4)));

__device__ __forceinline__ float4 ld4(const float* p) { return *(const float4*)p; }

// f16 weight arena offsets (elements)
#define oW1l 0        // 128x128
#define oW1r 16384    // 128x128
#define oW2l 32768    // 64x128
#define oW2r 40960    // 64x128
#define oW1a 49152    // 128x64   (pW1 cols 0..63, pre-scaled by bn2s[row])
#define oW1b 57344    // 128x64   (pW1 cols 64..127, pre-scaled)
#define oW1c 65536    // 128x32   (pW1 cols 128..159, pre-scaled)
#define oWe1 69632    // 64x32
#define oWe2 71680    // 32x64
#define oWp2 73728    // 64x128   (pW2, pre-scaled by bn3s[row])
#define W16_TOTAL 81920

#define BN_TOTAL 608

// CSR build params: coarse buckets of 512 nodes, block-local multisplit
#define BSH 9                      // bucket = dst >> 9
#define NB2 196                    // ceil(100000 / 512)
#define SCAP2 9216                 // per-bucket stage capacity (mean 8192, +11 sigma)
#define ECHUNK 4096                // edges per bucketA block
#define NCHUNK ((Ee + ECHUNK - 1) / ECHUNK)   // 391

// ---------------- prep: f32 -> f16 weights/x + BN const folding ----------------
// pW1 / pW2 copies are PRE-SCALED by their BN scale (bn2s/bn3s) so the edge
// kernel needs no per-channel scale, only the additive const from bnA.
__global__ __launch_bounds__(256) void prep_kernel(
    const float* __restrict__ x,
    const float* __restrict__ s1Wl, const float* __restrict__ s1Wr,
    const float* __restrict__ s2Wl, const float* __restrict__ s2Wr,
    const float* __restrict__ pW1,  const float* __restrict__ eW1,
    const float* __restrict__ eW2,  const float* __restrict__ pW2,
    const float* __restrict__ eb1,
    const float* __restrict__ ebng, const float* __restrict__ ebnb,
    const float* __restrict__ ebnm, const float* __restrict__ ebnv,
    const float* __restrict__ eb2,
    const float* __restrict__ pb1,
    const float* __restrict__ p1g, const float* __restrict__ p1b,
    const float* __restrict__ p1m, const float* __restrict__ p1v,
    const float* __restrict__ pb2,
    const float* __restrict__ p2g, const float* __restrict__ p2b,
    const float* __restrict__ p2m, const float* __restrict__ p2v,
    const float* __restrict__ pW3,
    _Float16* __restrict__ w16, float* __restrict__ bnA,
    _Float16* __restrict__ x16) {
    int tid = blockIdx.x * 256 + threadIdx.x;
    if (tid < W16_TOTAL) {
        float v;
        if (tid < 16384)      v = s1Wl[tid];
        else if (tid < 32768) v = s1Wr[tid - 16384];
        else if (tid < 40960) v = s2Wl[tid - 32768];
        else if (tid < 49152) v = s2Wr[tid - 40960];
        else if (tid < 57344) { int l = tid - 49152; int r = l >> 6;
                                v = pW1[r * 160 + (l & 63)] * (p1g[r] * rsqrtf(p1v[r] + EPSf)); }
        else if (tid < 65536) { int l = tid - 57344; int r = l >> 6;
                                v = pW1[r * 160 + 64 + (l & 63)] * (p1g[r] * rsqrtf(p1v[r] + EPSf)); }
        else if (tid < 69632) { int l = tid - 65536; int r = l >> 5;
                                v = pW1[r * 160 + 128 + (l & 31)] * (p1g[r] * rsqrtf(p1v[r] + EPSf)); }
        else if (tid < 71680) v = eW1[tid - 69632];
        else if (tid < 73728) v = eW2[tid - 71680];
        else                  { int l = tid - 73728; int r = l >> 7;
                                v = pW2[l] * (p2g[r] * rsqrtf(p2v[r] + EPSf)); }
        w16[tid] = (_Float16)v;
    } else if (tid < W16_TOTAL + BN_TOTAL) {
        int b = tid - W16_TOTAL;
        float v;
        if (b < 64)       v = ebng[b] * rsqrtf(ebnv[b] + EPSf);
        else if (b < 128) { int c = b - 64;  float s = ebng[c] * rsqrtf(ebnv[c] + EPSf);
                            v = (eb1[c] - ebnm[c]) * s + ebnb[c]; }
        else if (b < 256) { int c = b - 128; v = p1g[c] * rsqrtf(p1v[c] + EPSf); }
        else if (b < 384) { int c = b - 256; float s = p1g[c] * rsqrtf(p1v[c] + EPSf);
                            v = (pb1[c] - p1m[c]) * s + p1b[c]; }
        else if (b < 448) { int c = b - 384; v = p2g[c] * rsqrtf(p2v[c] + EPSf); }
        else if (b < 512) { int c = b - 448; float s = p2g[c] * rsqrtf(p2v[c] + EPSf);
                            v = (pb2[c] - p2m[c]) * s + p2b[c]; }
        else if (b < 544) v = eb2[b - 512];
        else              v = pW3[b - 544];
        bnA[b] = v;
    }
    int stride = gridDim.x * 256;
    const int NV = Nn * 128 / 4;
    for (int i = tid; i < NV; i += stride) {
        float4 v = ((const float4*)x)[i];
        f16x4 h = {(_Float16)v.x, (_Float16)v.y, (_Float16)v.z, (_Float16)v.w};
        ((f16x4*)x16)[i] = h;
    }
}

// ---------------- CSR build pass A: block-local multisplit into coarse buckets ----
__global__ __launch_bounds__(256) void bucketA_kernel(
    const int* __restrict__ src, const int* __restrict__ dst,
    unsigned* __restrict__ stage, unsigned* __restrict__ gcur) {
    __shared__ unsigned hist[NB2];
    __shared__ unsigned base[NB2];
    const int t = threadIdx.x;
    const int e0 = blockIdx.x * ECHUNK;
    for (int u = t; u < NB2; u += 256) hist[u] = 0u;
    __syncthreads();

    int sv[16], dv[16];
#pragma unroll
    for (int k = 0; k < 16; ++k) {
        int e = e0 + k * 256 + t;
        if (e < Ee) {
            sv[k] = src[e];
            dv[k] = dst[e];
            atomicAdd(&hist[dv[k] >> BSH], 1u);
        } else dv[k] = -1;
    }
    __syncthreads();
    for (int u = t; u < NB2; u += 256) {
        unsigned h = hist[u];
        base[u] = h ? atomicAdd(&gcur[u], h) : 0u;
        hist[u] = 0u;
    }
    __syncthreads();
#pragma unroll
    for (int k = 0; k < 16; ++k) {
        if (dv[k] >= 0) {
            int b = dv[k] >> BSH;
            unsigned p = atomicAdd(&hist[b], 1u);
            stage[(size_t)b * SCAP2 + base[b] + p] =
                ((unsigned)sv[k] << BSH) | (unsigned)(dv[k] & 511);
        }
    }
}

// ---------------- CSR pass C: per-bucket node counts -> deg (coalesced) ----
__global__ __launch_bounds__(256) void countC_kernel(
    const unsigned* __restrict__ stage, const unsigned* __restrict__ gcur,
    unsigned* __restrict__ deg) {
    __shared__ unsigned cnt[512];
    const int b = blockIdx.x;
    const int t = threadIdx.x;
    cnt[t] = 0u; cnt[t + 256] = 0u;
    __syncthreads();
    unsigned m = gcur[b];
    const unsigned* sp = stage + (size_t)b * SCAP2;
    for (unsigned i = t; i < m; i += 256)
        atomicAdd(&cnt[sp[i] & 511], 1u);
    __syncthreads();
    int n0 = b << BSH;
    if (n0 + t < Nn)       deg[n0 + t] = cnt[t];
    if (n0 + 256 + t < Nn) deg[n0 + 256 + t] = cnt[t + 256];
}

__global__ __launch_bounds__(1024) void scanA_kernel(const unsigned* __restrict__ deg,
                                                     unsigned* __restrict__ escan,
                                                     unsigned* __restrict__ bsum) {
    __shared__ unsigned s[1024];
    int t = threadIdx.x;
    int gid = blockIdx.x * 1024 + t;
    unsigned v = (gid < Nn) ? deg[gid] : 0u;
    s[t] = v;
    __syncthreads();
    for (int off = 1; off < 1024; off <<= 1) {
        unsigned u = (t >= off) ? s[t - off] : 0u;
        __syncthreads();
        s[t] += u;
        __syncthreads();
    }
    if (gid < Nn) escan[gid] = s[t] - v;
    if (t == 1023) bsum[blockIdx.x] = s[1023];
}

__global__ __launch_bounds__(128) void scanB_kernel(const unsigned* __restrict__ bsum,
                                                    unsigned* __restrict__ boff,
                                                    int nblk) {
    __shared__ unsigned s[128];
    int t = threadIdx.x;
    unsigned v = (t < nblk) ? bsum[t] : 0u;
    s[t] = v;
    __syncthreads();
    for (int off = 1; off < 128; off <<= 1) {
        unsigned u = (t >= off) ? s[t - off] : 0u;
        __syncthreads();
        s[t] += u;
        __syncthreads();
    }
    if (t < nblk) boff[t] = s[t] - v;
}

__global__ __launch_bounds__(1024) void scanC_kernel(const unsigned* __restrict__ escan,
                                                     const unsigned* __restrict__ boff,
                                                     int* __restrict__ rowptr) {
    int t = threadIdx.x;
    int gid = blockIdx.x * 1024 + t;
    if (gid < Nn) rowptr[gid] = (int)(escan[gid] + boff[blockIdx.x]);
    if (gid == 0) rowptr[Nn] = Ee;
}

// ---------------- CSR pass E: bucket-local scatter into elist ----
__global__ __launch_bounds__(256) void scatterE_kernel(
    const unsigned* __restrict__ stage, const unsigned* __restrict__ gcur,
    const int* __restrict__ rowptr, int* __restrict__ elist) {
    __shared__ int lbase[512];
    __shared__ unsigned cur[512];
    const int b = blockIdx.x;
    const int t = threadIdx.x;
    const int n0 = b << BSH;
    lbase[t]       = (n0 + t < Nn)       ? rowptr[n0 + t]       : 0;
    lbase[t + 256] = (n0 + 256 + t < Nn) ? rowptr[n0 + 256 + t] : 0;
    cur[t] = 0u; cur[t + 256] = 0u;
    __syncthreads();
    unsigned m = gcur[b];
    const unsigned* sp = stage + (size_t)b * SCAP2;
    for (unsigned i = t; i < m; i += 256) {
        unsigned v = sp[i];
        int lid = v & 511;
        unsigned p = atomicAdd(&cur[lid], 1u);
        elist[lbase[lid] + p] = (int)(v >> BSH);
    }
}

// ---------------- f16 mean aggregation ----------------
template<int W>
__global__ __launch_bounds__(256, 8) void aggregate16_kernel(
    const _Float16* __restrict__ feat,
    const int* __restrict__ rowptr,
    const int* __restrict__ elist,
    _Float16* __restrict__ outp) {
    int node = (blockIdx.x * 256 + threadIdx.x) >> 6;
    int lane = threadIdx.x & 63;
    if (node >= Nn) return;
    constexpr int SEGS = W / 8;
    constexpr int RPI  = 64 / SEGS;
    const int r = lane / SEGS, c = lane % SEGS;
    int beg = rowptr[node], end = rowptr[node + 1];
    int n = end - beg;
    float acc[8];
#pragma unroll
    for (int k = 0; k < 8; ++k) acc[k] = 0.f;
    for (int c0 = 0; c0 < n; c0 += 64) {
        int m = min(64, n - c0);
        int se = (lane < m) ? elist[beg + c0 + lane] : 0;
        int iters = (m + RPI - 1) / RPI;
#pragma unroll 2
        for (int i = 0; i < iters; ++i) {
            int j = i * RPI + r;
            int s = __shfl(se, j);
            if (j < m) {
                f16x8 v = *(const f16x8*)(feat + (size_t)s * W + c * 8);
#pragma unroll
                for (int k = 0; k < 8; ++k) acc[k] += (float)v[k];
            }
        }
    }
#pragma unroll
    for (int k = 0; k < 8; ++k) {
#pragma unroll
        for (int off = SEGS; off < 64; off <<= 1)
            acc[k] += __shfl_xor(acc[k], off);
    }
    if (r == 0) {
        float inv = 1.0f / fmaxf((float)n, 1.0f);
        f16x8 o;
#pragma unroll
        for (int k = 0; k < 8; ++k) o[k] = (_Float16)(acc[k] * inv);
        *(f16x8*)(outp + (size_t)node * W + c * 8) = o;
    }
}

// ---------------- dense SAGE layer 1 via MFMA ----------------
__global__ __launch_bounds__(256) void dense1_kernel(
    const _Float16* __restrict__ A1, const _Float16* __restrict__ A2,
    const _Float16* __restrict__ W1, const _Float16* __restrict__ W2,
    const float* __restrict__ lb,
    const float* __restrict__ bng, const float* __restrict__ bnb,
    const float* __restrict__ bnm, const float* __restrict__ bnv,
    _Float16* __restrict__ out) {
    const int t = threadIdx.x;
    const int w = t >> 6, lane = t & 63;
    const int lrow = lane & 15, lq = lane >> 4;
    const int row0 = blockIdx.x * 64 + w * 16;
    const int ld = min(row0 + lrow, Nn - 1);

    f16x8 a1[4], a2[4];
#pragma unroll
    for (int i = 0; i < 4; ++i) {
        a1[i] = *(const f16x8*)(A1 + (size_t)ld * 128 + i * 32 + lq * 8);
        a2[i] = *(const f16x8*)(A2 + (size_t)ld * 128 + i * 32 + lq * 8);
    }
#pragma unroll
    for (int nt = 0; nt < 8; ++nt) {
        const _Float16* w1r = W1 + (size_t)(nt * 16 + lrow) * 128;
        const _Float16* w2r = W2 + (size_t)(nt * 16 + lrow) * 128;
        f32x4 c = {0.f, 0.f, 0.f, 0.f};
#pragma unroll
        for (int i = 0; i < 4; ++i) {
            c = __builtin_amdgcn_mfma_f32_16x16x32_f16(a1[i], *(const f16x8*)(w1r + i * 32 + lq * 8), c, 0, 0, 0);
            c = __builtin_amdgcn_mfma_f32_16x16x32_f16(a2[i], *(const f16x8*)(w2r + i * 32 + lq * 8), c, 0, 0, 0);
        }
        int cc = nt * 16 + lrow;
        float s = bng[cc] * rsqrtf(bnv[cc] + EPSf);
        float h = (lb[cc] - bnm[cc]) * s + bnb[cc];
#pragma unroll
        for (int r = 0; r < 4; ++r) {
            int gr = row0 + lq * 4 + r;
            if (gr < Nn)
                out[(size_t)gr * 128 + cc] = (_Float16)fmaxf(c[r] * s + h, 0.f);
        }
    }
}

// ---------------- y = h @ W2l^T ----------------
__global__ __launch_bounds__(256) void gemmY_kernel(
    const _Float16* __restrict__ A, const _Float16* __restrict__ W,
    _Float16* __restrict__ out) {
    const int t = threadIdx.x;
    const int w = t >> 6, lane = t & 63;
    const int lrow = lane & 15, lq = lane >> 4;
    const int row0 = blockIdx.x * 64 + w * 16;
    const int ld = min(row0 + lrow, Nn - 1);
    f16x8 a[4];
#pragma unroll
    for (int i = 0; i < 4; ++i)
        a[i] = *(const f16x8*)(A + (size_t)ld * 128 + i * 32 + lq * 8);
#pragma unroll
    for (int nt = 0; nt < 4; ++nt) {
        const _Float16* wr = W + (size_t)(nt * 16 + lrow) * 128;
        f32x4 c = {0.f, 0.f, 0.f, 0.f};
#pragma unroll
        for (int i = 0; i < 4; ++i)
            c = __builtin_amdgcn_mfma_f32_16x16x32_f16(a[i], *(const f16x8*)(wr + i * 32 + lq * 8), c, 0, 0, 0);
        int cc = nt * 16 + lrow;
#pragma unroll
        for (int r = 0; r < 4; ++r) {
            int gr = row0 + lq * 4 + r;
            if (gr < Nn) out[(size_t)gr * 64 + cc] = (_Float16)c[r];
        }
    }
}

// ---------------- z = aggY + h @ W2r^T + lb ----------------
__global__ __launch_bounds__(256) void dense2b_kernel(
    const _Float16* __restrict__ aggY, const _Float16* __restrict__ A2,
    const _Float16* __restrict__ W2, const float* __restrict__ lb,
    _Float16* __restrict__ out) {
    const int t = threadIdx.x;
    const int w = t >> 6, lane = t & 63;
    const int lrow = lane & 15, lq = lane >> 4;
    const int row0 = blockIdx.x * 64 + w * 16;
    const int ld = min(row0 + lrow, Nn - 1);
    f16x8 a[4];
#pragma unroll
    for (int i = 0; i < 4; ++i)
        a[i] = *(const f16x8*)(A2 + (size_t)ld * 128 + i * 32 + lq * 8);
#pragma unroll
    for (int nt = 0; nt < 4; ++nt) {
        const _Float16* wr = W2 + (size_t)(nt * 16 + lrow) * 128;
        f32x4 c = {0.f, 0.f, 0.f, 0.f};
#pragma unroll
        for (int i = 0; i < 4; ++i)
            c = __builtin_amdgcn_mfma_f32_16x16x32_f16(a[i], *(const f16x8*)(wr + i * 32 + lq * 8), c, 0, 0, 0);
        int cc = nt * 16 + lrow;
        float b = lb[cc];
#pragma unroll
        for (int r = 0; r < 4; ++r) {
            int gr = row0 + lq * 4 + r;
            if (gr < Nn) {
                float g = (float)aggY[(size_t)gr * 64 + cc];
                out[(size_t)gr * 64 + cc] = (_Float16)(c[r] + g + b);
            }
        }
    }
}

// ---------------- edge-feature MLP: e2 = (relu(bn(ef@We1^T)))@We2^T + eb2 ----
__global__ __launch_bounds__(256) void emlp_kernel(
    const float* __restrict__ ef,
    const _Float16* __restrict__ w16,
    const float* __restrict__ bnA,
    _Float16* __restrict__ e2out) {
    __shared__ __align__(16) _Float16 E1[64 * 72];
    const int t = threadIdx.x;
    const int lane = t & 63, w = t >> 6;
    const int lrow = lane & 15, lq = lane >> 4;
    const int e0 = blockIdx.x * 64 + w * 16;
    const int erow = w * 16 + lrow;

    const float* src = ef + (size_t)(e0 + lrow) * 32 + lq * 8;
    float4 f0 = ld4(src), f1 = ld4(src + 4);
    f16x8 bf = {(_Float16)f0.x, (_Float16)f0.y, (_Float16)f0.z, (_Float16)f0.w,
                (_Float16)f1.x, (_Float16)f1.y, (_Float16)f1.z, (_Float16)f1.w};

#pragma unroll
    for (int nt = 0; nt < 4; ++nt) {
        f16x8 wf = *(const f16x8*)(w16 + oWe1 + (nt * 16 + lrow) * 32 + lq * 8);
        f32x4 c = {0.f, 0.f, 0.f, 0.f};
        c = __builtin_amdgcn_mfma_f32_16x16x32_f16(wf, bf, c, 0, 0, 0);
        int cb = nt * 16 + lq * 4;
        float4 s = *(const float4*)(bnA + cb);
        float4 h = *(const float4*)(bnA + 64 + cb);
        f16x4 o;
        o[0] = (_Float16)fmaxf(c[0] * s.x + h.x, 0.f);
        o[1] = (_Float16)fmaxf(c[1] * s.y + h.y, 0.f);
        o[2] = (_Float16)fmaxf(c[2] * s.z + h.z, 0.f);
        o[3] = (_Float16)fmaxf(c[3] * s.w + h.w, 0.f);
        *(f16x4*)(E1 + erow * 72 + cb) = o;
    }
    f16x8 a0 = *(const f16x8*)(E1 + erow * 72 + lq * 8);
    f16x8 a1 = *(const f16x8*)(E1 + erow * 72 + 32 + lq * 8);
#pragma unroll
    for (int nt = 0; nt < 2; ++nt) {
        f16x8 b0 = *(const f16x8*)(w16 + oWe2 + (nt * 16 + lrow) * 64 + lq * 8);
        f16x8 b1 = *(const f16x8*)(w16 + oWe2 + (nt * 16 + lrow) * 64 + 32 + lq * 8);
        f32x4 c = {0.f, 0.f, 0.f, 0.f};
        c = __builtin_amdgcn_mfma_f32_16x16x32_f16(b0, a0, c, 0, 0, 0);
        c = __builtin_amdgcn_mfma_f32_16x16x32_f16(b1, a1, c, 0, 0, 0);
        int cb = nt * 16 + lq * 4;
        float4 bias = *(const float4*)(bnA + 512 + cb);
        f16x4 o;
        o[0] = (_Float16)(c[0] + bias.x);
        o[1] = (_Float16)(c[1] + bias.y);
        o[2] = (_Float16)(c[2] + bias.z);
        o[3] = (_Float16)(c[3] + bias.w);
        *(f16x4*)(e2out + (size_t)(e0 + lrow) * 32 + cb) = o;
    }
}

// ---------------- fused predictor v5: 2 blocks/CU via chunked-ZU transpose ----
// Per p in 0..3: P4's nt-pair (2p,2p+1) produces EXACTLY the 32-channel slice
// P6's k-chunk p consumes -> ZU shrinks [256][136] -> [256][32] (XOR-16B
// swizzle). BN scales folded into weights at prep; additive consts from
// L1-hot global bnA. No data prefetch (32-wave TLP hides gather latency).
// LDS = 80896 B -> 2 blocks/CU; __launch_bounds__(1024,8) pins VGPR <= 64.
#define EPB 256
#define NT  ((Pp + EPB - 1) / EPB)     // 3907
#define EGRID 512

#define oL_W1a 0        // [128][72]  18432
#define oL_W1b 18432    // [128][72]  18432
#define oL_W1c 36864    // [128][40]  10240
#define oL_Wp2 47104    // [64][136]  17408
#define oL_ZU  64512    // [256][32]  16384  (XOR-16B swizzled)
#define SMEM_BYTES 80896

__global__ __launch_bounds__(1024, 8) void edge_kernel(
    const int* __restrict__ pe,
    const _Float16* __restrict__ e2,     // [P,32]
    const _Float16* __restrict__ z,      // [N,64]
    const _Float16* __restrict__ w16,
    const float* __restrict__ bnA,
    const float* __restrict__ pb3,
    float* __restrict__ out) {
    __shared__ __align__(16) unsigned char smem[SMEM_BYTES];
    _Float16* LW1a = (_Float16*)(smem + oL_W1a);
    _Float16* LW1b = (_Float16*)(smem + oL_W1b);
    _Float16* LW1c = (_Float16*)(smem + oL_W1c);
    _Float16* LWp2 = (_Float16*)(smem + oL_Wp2);
    unsigned char* ZU = smem + oL_ZU;

    const int t = threadIdx.x;
    const int lane = t & 63;
    const int w = t >> 6;          // 0..15
    const int m0 = w * 16;
    const int lrow = lane & 15;
    const int lq = lane >> 4;
    const float pb3v = pb3[0];

    // ---- stage pre-scaled weights into LDS ----
    { int r = t >> 3, s = t & 7;
      *(f16x8*)(LW1a + r * 72 + s * 8) = *(const f16x8*)(w16 + oW1a + r * 64 + s * 8);
      *(f16x8*)(LW1b + r * 72 + s * 8) = *(const f16x8*)(w16 + oW1b + r * 64 + s * 8); }
    if (t < 512) { int r = t >> 2, s = t & 3;
      *(f16x8*)(LW1c + r * 40 + s * 8) = *(const f16x8*)(w16 + oW1c + r * 32 + s * 8); }
    { int r = t >> 4, s = t & 15;
      *(f16x8*)(LWp2 + r * 136 + s * 8) = *(const f16x8*)(w16 + oWp2 + r * 128 + s * 8); }
    __syncthreads();

    const int erow = m0 + lrow;
    unsigned char* zrow = ZU + erow * 64;           // 32 f16 = 64 B per row
    const int zswz = (erow & 3) << 4;               // XOR-16B swizzle

    int tile = blockIdx.x;
    int ia, ib;
    { int e = min(tile * EPB + m0 + lrow, Pp - 1);
      ia = pe[e]; ib = pe[Pp + e]; }

    for (; tile < NT; tile += EGRID) {
        const int e_cur = tile * EPB + m0;
        // ---- gather fragments for this tile (TLP hides latency) ----
        f16x8 F0 = *(const f16x8*)(z + (size_t)ia * 64 + lq * 8);
        f16x8 F1 = *(const f16x8*)(z + (size_t)ia * 64 + 32 + lq * 8);
        f16x8 F2 = *(const f16x8*)(z + (size_t)ib * 64 + lq * 8);
        f16x8 F3 = *(const f16x8*)(z + (size_t)ib * 64 + 32 + lq * 8);
        f16x8 F4;
        { int e = min(e_cur + lrow, Pp - 1);
          F4 = *(const f16x8*)(e2 + (size_t)e * 32 + lq * 8); }
        // ---- prefetch next tile's indices ----
        { int tl = tile + EGRID;
          if (tl < NT) { int e = min(tl * EPB + m0 + lrow, Pp - 1);
                         ia = pe[e]; ib = pe[Pp + e]; } }

        if (e_cur < Pp) {
            f32x4 c6[4] = {{0.f,0.f,0.f,0.f},{0.f,0.f,0.f,0.f},
                           {0.f,0.f,0.f,0.f},{0.f,0.f,0.f,0.f}};
            __builtin_amdgcn_s_setprio(1);
#pragma unroll
            for (int p = 0; p < 4; ++p) {
                // P4 pair nt = 2p, 2p+1 -> chunk p of u1 (channels 32p..32p+31)
#pragma unroll
                for (int h2 = 0; h2 < 2; ++h2) {
                    const int nt = 2 * p + h2;
                    const _Float16* wa = LW1a + (nt * 16 + lrow) * 72;
                    const _Float16* wb = LW1b + (nt * 16 + lrow) * 72;
                    const _Float16* wc = LW1c + (nt * 16 + lrow) * 40;
                    f32x4 c = {0.f, 0.f, 0.f, 0.f};
                    c = __builtin_amdgcn_mfma_f32_16x16x32_f16(*(const f16x8*)(wa + lq * 8),      F0, c, 0, 0, 0);
                    c = __builtin_amdgcn_mfma_f32_16x16x32_f16(*(const f16x8*)(wa + 32 + lq * 8), F1, c, 0, 0, 0);
                    c = __builtin_amdgcn_mfma_f32_16x16x32_f16(*(const f16x8*)(wb + lq * 8),      F2, c, 0, 0, 0);
                    c = __builtin_amdgcn_mfma_f32_16x16x32_f16(*(const f16x8*)(wb + 32 + lq * 8), F3, c, 0, 0, 0);
                    c = __builtin_amdgcn_mfma_f32_16x16x32_f16(*(const f16x8*)(wc + lq * 8),      F4, c, 0, 0, 0);
                    float4 hh = *(const float4*)(bnA + 256 + nt * 16 + lq * 4);
                    f16x4 o;
                    o[0] = (_Float16)fmaxf(c[0] + hh.x, 0.f);
                    o[1] = (_Float16)fmaxf(c[1] + hh.y, 0.f);
                    o[2] = (_Float16)fmaxf(c[2] + hh.z, 0.f);
                    o[3] = (_Float16)fmaxf(c[3] + hh.w, 0.f);
                    *(f16x4*)(zrow + ((h2 * 32 + lq * 8) ^ zswz)) = o;
                }
                // read back chunk-p fragment (cross-lane via wave-private LDS rows)
                f16x8 a = *(const f16x8*)(zrow + ((lq * 16) ^ zswz));
#pragma unroll
                for (int nt2 = 0; nt2 < 4; ++nt2) {
                    const _Float16* wr = LWp2 + (nt2 * 16 + lrow) * 136 + p * 32 + lq * 8;
                    c6[nt2] = __builtin_amdgcn_mfma_f32_16x16x32_f16(*(const f16x8*)(wr), a, c6[nt2], 0, 0, 0);
                }
            }
            __builtin_amdgcn_s_setprio(0);
            // ---- fused epilogue: u2 = relu(c6 + bn3h); out = u2 . wp3 + pb3 ----
            float acc = 0.f;
#pragma unroll
            for (int nt2 = 0; nt2 < 4; ++nt2) {
                int cb = nt2 * 16 + lq * 4;
                float4 h3 = *(const float4*)(bnA + 448 + cb);
                float4 w3 = *(const float4*)(bnA + 544 + cb);
                acc += fmaxf(c6[nt2][0] + h3.x, 0.f) * w3.x;
                acc += fmaxf(c6[nt2][1] + h3.y, 0.f) * w3.y;
                acc += fmaxf(c6[nt2][2] + h3.z, 0.f) * w3.z;
                acc += fmaxf(c6[nt2][3] + h3.w, 0.f) * w3.w;
            }
            acc += __shfl_xor(acc, 16);
            acc += __shfl_xor(acc, 32);
            if (lane < 16) out[e_cur + lane] = acc + pb3v;
        }
    }
}

// ---------------- launch ----------------
extern "C" void kernel_launch(void* const* d_in, const int* in_sizes, int n_in,
                              void* d_out, int out_size, void* d_ws, size_t ws_size,
                              hipStream_t stream) {
    const float* x    = (const float*)d_in[0];
    const int*   eidx = (const int*)d_in[1];
    const int*   pe   = (const int*)d_in[2];
    const float* ef   = (const float*)d_in[3];
    const float* s1Wl = (const float*)d_in[4];
    const float* s1bl = (const float*)d_in[5];
    const float* s1Wr = (const float*)d_in[6];
    const float* bn1g = (const float*)d_in[7];
    const float* bn1b = (const float*)d_in[8];
    const float* bn1m = (const float*)d_in[9];
    const float* bn1v = (const float*)d_in[10];
    const float* s2Wl = (const float*)d_in[11];
    const float* s2bl = (const float*)d_in[12];
    const float* s2Wr = (const float*)d_in[13];
    const float* eW1  = (const float*)d_in[14];
    const float* eb1  = (const float*)d_in[15];
    const float* ebng = (const float*)d_in[16];
    const float* ebnb = (const float*)d_in[17];
    const float* ebnm = (const float*)d_in[18];
    const float* ebnv = (const float*)d_in[19];
    const float* eW2  = (const float*)d_in[20];
    const float* eb2  = (const float*)d_in[21];
    const float* pW1  = (const float*)d_in[22];
    const float* pb1  = (const float*)d_in[23];
    const float* p1g  = (const float*)d_in[24];
    const float* p1b  = (const float*)d_in[25];
    const float* p1m  = (const float*)d_in[26];
    const float* p1v  = (const float*)d_in[27];
    const float* pW2  = (const float*)d_in[28];
    const float* pb2  = (const float*)d_in[29];
    const float* p2g  = (const float*)d_in[30];
    const float* p2b  = (const float*)d_in[31];
    const float* p2m  = (const float*)d_in[32];
    const float* p2v  = (const float*)d_in[33];
    const float* pW3  = (const float*)d_in[34];
    const float* pb3  = (const float*)d_in[35];
    float* out = (float*)d_out;

    char* wk = (char*)d_ws;
    auto carve = [&](size_t bytes) {
        char* p = wk;
        wk += (bytes + 255) & ~(size_t)255;
        return p;
    };
    unsigned*  deg    = (unsigned*)carve((size_t)Nn * 4);
    unsigned*  gcur   = (unsigned*)carve((size_t)256 * 4);
    int*       rowptr = (int*)carve((size_t)(Nn + 1) * 4);
    int*       elist  = (int*)carve((size_t)Ee * 4);
    unsigned*  escan  = (unsigned*)carve((size_t)Nn * 4);
    unsigned*  bsum   = (unsigned*)carve(128 * 4);
    unsigned*  boff   = (unsigned*)carve(128 * 4);
    _Float16*  w16    = (_Float16*)carve((size_t)W16_TOTAL * 2);
    float*     bnA    = (float*)carve((size_t)BN_TOTAL * 4);
    _Float16*  bufX   = (_Float16*)carve((size_t)Nn * 128 * 2);  // x16; later y|z
    _Float16*  bufA   = (_Float16*)carve((size_t)Nn * 128 * 2);  // agg1 out; later aggY
    _Float16*  bufH   = (_Float16*)carve((size_t)Nn * 128 * 2);  // h (dead during CSR build)
    _Float16*  e2buf  = (_Float16*)carve((size_t)Pp * 32 * 2);   // edge MLP out
    _Float16*  bufY   = bufX;
    _Float16*  bufZ   = bufX + (size_t)Nn * 64;
    _Float16*  bufAy  = bufA;
    unsigned*  stage  = (unsigned*)bufH;   // alias: 7.2 MB <= 25.6 MB, dead here

    const int* e_src = eidx;
    const int* e_dst = eidx + Ee;
    const int SBLK = (Nn + 1023) / 1024;   // 98

    hipMemsetAsync(gcur, 0, 256 * 4, stream);

    prep_kernel<<<800, 256, 0, stream>>>(x, s1Wl, s1Wr, s2Wl, s2Wr, pW1, eW1, eW2, pW2,
                                         eb1, ebng, ebnb, ebnm, ebnv, eb2,
                                         pb1, p1g, p1b, p1m, p1v,
                                         pb2, p2g, p2b, p2m, p2v, pW3,
                                         w16, bnA, bufX);
    // edge-feature MLP (independent of graph; streaming)
    emlp_kernel<<<Pp / 64, 256, 0, stream>>>(ef, w16, bnA, e2buf);

    // CSR build: block-local multisplit (no per-edge global atomics)
    bucketA_kernel<<<NCHUNK, 256, 0, stream>>>(e_src, e_dst, stage, gcur);
    countC_kernel<<<NB2, 256, 0, stream>>>(stage, gcur, deg);
    scanA_kernel<<<SBLK, 1024, 0, stream>>>(deg, escan, bsum);
    scanB_kernel<<<1, 128, 0, stream>>>(bsum, boff, SBLK);
    scanC_kernel<<<SBLK, 1024, 0, stream>>>(escan, boff, rowptr);
    scatterE_kernel<<<NB2, 256, 0, stream>>>(stage, gcur, rowptr, elist);

    // SAGE layer 1
    aggregate16_kernel<128><<<Nn / 4, 256, 0, stream>>>(bufX, rowptr, elist, bufA);
    dense1_kernel<<<(Nn + 63) / 64, 256, 0, stream>>>(
        bufA, bufX, w16 + oW1l, w16 + oW1r, s1bl, bn1g, bn1b, bn1m, bn1v, bufH);

    // SAGE layer 2 (linear commutes with mean)
    gemmY_kernel<<<(Nn + 63) / 64, 256, 0, stream>>>(bufH, w16 + oW2l, bufY);
    aggregate16_kernel<64><<<Nn / 4, 256, 0, stream>>>(bufY, rowptr, elist, bufAy);
    dense2b_kernel<<<(Nn + 63) / 64, 256, 0, stream>>>(
        bufAy, bufH, w16 + oW2r, s2bl, bufZ);

    // fused per-edge predictor (2 blocks/CU, chunked-ZU transpose)
    edge_kernel<<<EGRID, 1024, 0, stream>>>(pe, e2buf, bufZ, w16, bnA, pb3, out);
}

// Round 6
// 670.620 us; speedup vs baseline: 1.0244x; 1.0244x over previous
//
#include <hip/hip_runtime.h>

#define Nn 100000
#define Ee 1600000
#define Pp 1000000
#define EPSf 1e-5f

typedef _Float16 f16x8 __attribute__((ext_vector_type(8)));
typedef _Float16 f16x4 __attribute__((ext_vector_type(4)));
typedef _Float16 f16x2 __attribute__((ext_vector_type(2)));
typedef float f32x4 __attribute__((ext_vector_type(4)));

__device__ __forceinline__ float4 ld4(const float* p) { return *(const float4*)p; }

// f16 weight arena offsets (elements)
#define oW1l 0        // 128x128
#define oW1r 16384    // 128x128
#define oW2l 32768    // 64x128
#define oW2r 40960    // 64x128
#define oW1a 49152    // 128x64   (pW1 cols 0..63)
#define oW1b 57344    // 128x64   (pW1 cols 64..127)
#define oW1c 65536    // 128x32   (pW1 cols 128..159)
#define oWe1 69632    // 64x32
#define oWe2 71680    // 32x64
#define oWp2 73728    // 64x128
#define W16_TOTAL 81920

#define BN_TOTAL 608

// CSR build params: coarse buckets of 512 nodes, block-local multisplit
#define BSH 9                      // bucket = dst >> 9
#define NB2 196                    // ceil(100000 / 512)
#define SCAP2 9216                 // per-bucket stage capacity (mean 8192, +11 sigma)
#define ECHUNK 4096                // edges per bucketA block
#define NCHUNK ((Ee + ECHUNK - 1) / ECHUNK)   // 391

// ---------------- prep: f32 -> f16 weights/x + BN const folding ----------------
__global__ __launch_bounds__(256) void prep_kernel(
    const float* __restrict__ x,
    const float* __restrict__ s1Wl, const float* __restrict__ s1Wr,
    const float* __restrict__ s2Wl, const float* __restrict__ s2Wr,
    const float* __restrict__ pW1,  const float* __restrict__ eW1,
    const float* __restrict__ eW2,  const float* __restrict__ pW2,
    const float* __restrict__ eb1,
    const float* __restrict__ ebng, const float* __restrict__ ebnb,
    const float* __restrict__ ebnm, const float* __restrict__ ebnv,
    const float* __restrict__ eb2,
    const float* __restrict__ pb1,
    const float* __restrict__ p1g, const float* __restrict__ p1b,
    const float* __restrict__ p1m, const float* __restrict__ p1v,
    const float* __restrict__ pb2,
    const float* __restrict__ p2g, const float* __restrict__ p2b,
    const float* __restrict__ p2m, const float* __restrict__ p2v,
    const float* __restrict__ pW3,
    _Float16* __restrict__ w16, float* __restrict__ bnA,
    _Float16* __restrict__ x16) {
    int tid = blockIdx.x * 256 + threadIdx.x;
    if (tid < W16_TOTAL) {
        float v;
        if (tid < 16384)      v = s1Wl[tid];
        else if (tid < 32768) v = s1Wr[tid - 16384];
        else if (tid < 40960) v = s2Wl[tid - 32768];
        else if (tid < 49152) v = s2Wr[tid - 40960];
        else if (tid < 57344) { int l = tid - 49152; v = pW1[(l >> 6) * 160 + (l & 63)]; }
        else if (tid < 65536) { int l = tid - 57344; v = pW1[(l >> 6) * 160 + 64 + (l & 63)]; }
        else if (tid < 69632) { int l = tid - 65536; v = pW1[(l >> 5) * 160 + 128 + (l & 31)]; }
        else if (tid < 71680) v = eW1[tid - 69632];
        else if (tid < 73728) v = eW2[tid - 71680];
        else                  v = pW2[tid - 73728];
        w16[tid] = (_Float16)v;
    } else if (tid < W16_TOTAL + BN_TOTAL) {
        int b = tid - W16_TOTAL;
        float v;
        if (b < 64)       v = ebng[b] * rsqrtf(ebnv[b] + EPSf);
        else if (b < 128) { int c = b - 64;  float s = ebng[c] * rsqrtf(ebnv[c] + EPSf);
                            v = (eb1[c] - ebnm[c]) * s + ebnb[c]; }
        else if (b < 256) { int c = b - 128; v = p1g[c] * rsqrtf(p1v[c] + EPSf); }
        else if (b < 384) { int c = b - 256; float s = p1g[c] * rsqrtf(p1v[c] + EPSf);
                            v = (pb1[c] - p1m[c]) * s + p1b[c]; }
        else if (b < 448) { int c = b - 384; v = p2g[c] * rsqrtf(p2v[c] + EPSf); }
        else if (b < 512) { int c = b - 448; float s = p2g[c] * rsqrtf(p2v[c] + EPSf);
                            v = (pb2[c] - p2m[c]) * s + p2b[c]; }
        else if (b < 544) v = eb2[b - 512];
        else              v = pW3[b - 544];
        bnA[b] = v;
    }
    int stride = gridDim.x * 256;
    const int NV = Nn * 128 / 4;
    for (int i = tid; i < NV; i += stride) {
        float4 v = ((const float4*)x)[i];
        f16x4 h = {(_Float16)v.x, (_Float16)v.y, (_Float16)v.z, (_Float16)v.w};
        ((f16x4*)x16)[i] = h;
    }
}

// ---------------- CSR build pass A: block-local multisplit into coarse buckets ----
__global__ __launch_bounds__(256) void bucketA_kernel(
    const int* __restrict__ src, const int* __restrict__ dst,
    unsigned* __restrict__ stage, unsigned* __restrict__ gcur) {
    __shared__ unsigned hist[NB2];
    __shared__ unsigned base[NB2];
    const int t = threadIdx.x;
    const int e0 = blockIdx.x * ECHUNK;
    for (int u = t; u < NB2; u += 256) hist[u] = 0u;
    __syncthreads();

    int sv[16], dv[16];
#pragma unroll
    for (int k = 0; k < 16; ++k) {
        int e = e0 + k * 256 + t;
        if (e < Ee) {
            sv[k] = src[e];
            dv[k] = dst[e];
            atomicAdd(&hist[dv[k] >> BSH], 1u);
        } else dv[k] = -1;
    }
    __syncthreads();
    for (int u = t; u < NB2; u += 256) {
        unsigned h = hist[u];
        base[u] = h ? atomicAdd(&gcur[u], h) : 0u;
        hist[u] = 0u;
    }
    __syncthreads();
#pragma unroll
    for (int k = 0; k < 16; ++k) {
        if (dv[k] >= 0) {
            int b = dv[k] >> BSH;
            unsigned p = atomicAdd(&hist[b], 1u);
            stage[(size_t)b * SCAP2 + base[b] + p] =
                ((unsigned)sv[k] << BSH) | (unsigned)(dv[k] & 511);
        }
    }
}

// ---------------- CSR pass C: per-bucket node counts -> deg (coalesced) ----
__global__ __launch_bounds__(256) void countC_kernel(
    const unsigned* __restrict__ stage, const unsigned* __restrict__ gcur,
    unsigned* __restrict__ deg) {
    __shared__ unsigned cnt[512];
    const int b = blockIdx.x;
    const int t = threadIdx.x;
    cnt[t] = 0u; cnt[t + 256] = 0u;
    __syncthreads();
    unsigned m = gcur[b];
    const unsigned* sp = stage + (size_t)b * SCAP2;
    for (unsigned i = t; i < m; i += 256)
        atomicAdd(&cnt[sp[i] & 511], 1u);
    __syncthreads();
    int n0 = b << BSH;
    if (n0 + t < Nn)       deg[n0 + t] = cnt[t];
    if (n0 + 256 + t < Nn) deg[n0 + 256 + t] = cnt[t + 256];
}

__global__ __launch_bounds__(1024) void scanA_kernel(const unsigned* __restrict__ deg,
                                                     unsigned* __restrict__ escan,
                                                     unsigned* __restrict__ bsum) {
    __shared__ unsigned s[1024];
    int t = threadIdx.x;
    int gid = blockIdx.x * 1024 + t;
    unsigned v = (gid < Nn) ? deg[gid] : 0u;
    s[t] = v;
    __syncthreads();
    for (int off = 1; off < 1024; off <<= 1) {
        unsigned u = (t >= off) ? s[t - off] : 0u;
        __syncthreads();
        s[t] += u;
        __syncthreads();
    }
    if (gid < Nn) escan[gid] = s[t] - v;
    if (t == 1023) bsum[blockIdx.x] = s[1023];
}

__global__ __launch_bounds__(128) void scanB_kernel(const unsigned* __restrict__ bsum,
                                                    unsigned* __restrict__ boff,
                                                    int nblk) {
    __shared__ unsigned s[128];
    int t = threadIdx.x;
    unsigned v = (t < nblk) ? bsum[t] : 0u;
    s[t] = v;
    __syncthreads();
    for (int off = 1; off < 128; off <<= 1) {
        unsigned u = (t >= off) ? s[t - off] : 0u;
        __syncthreads();
        s[t] += u;
        __syncthreads();
    }
    if (t < nblk) boff[t] = s[t] - v;
}

__global__ __launch_bounds__(1024) void scanC_kernel(const unsigned* __restrict__ escan,
                                                     const unsigned* __restrict__ boff,
                                                     int* __restrict__ rowptr) {
    int t = threadIdx.x;
    int gid = blockIdx.x * 1024 + t;
    if (gid < Nn) rowptr[gid] = (int)(escan[gid] + boff[blockIdx.x]);
    if (gid == 0) rowptr[Nn] = Ee;
}

// ---------------- CSR pass E: bucket-local scatter into elist ----
__global__ __launch_bounds__(256) void scatterE_kernel(
    const unsigned* __restrict__ stage, const unsigned* __restrict__ gcur,
    const int* __restrict__ rowptr, int* __restrict__ elist) {
    __shared__ int lbase[512];
    __shared__ unsigned cur[512];
    const int b = blockIdx.x;
    const int t = threadIdx.x;
    const int n0 = b << BSH;
    lbase[t]       = (n0 + t < Nn)       ? rowptr[n0 + t]       : 0;
    lbase[t + 256] = (n0 + 256 + t < Nn) ? rowptr[n0 + 256 + t] : 0;
    cur[t] = 0u; cur[t + 256] = 0u;
    __syncthreads();
    unsigned m = gcur[b];
    const unsigned* sp = stage + (size_t)b * SCAP2;
    for (unsigned i = t; i < m; i += 256) {
        unsigned v = sp[i];
        int lid = v & 511;
        unsigned p = atomicAdd(&cur[lid], 1u);
        elist[lbase[lid] + p] = (int)(v >> BSH);
    }
}

// ---------------- f16 mean aggregation (unroll 4: more gathers in flight) ----
template<int W>
__global__ __launch_bounds__(256, 8) void aggregate16_kernel(
    const _Float16* __restrict__ feat,
    const int* __restrict__ rowptr,
    const int* __restrict__ elist,
    _Float16* __restrict__ outp) {
    int node = (blockIdx.x * 256 + threadIdx.x) >> 6;
    int lane = threadIdx.x & 63;
    if (node >= Nn) return;
    constexpr int SEGS = W / 8;
    constexpr int RPI  = 64 / SEGS;
    const int r = lane / SEGS, c = lane % SEGS;
    int beg = rowptr[node], end = rowptr[node + 1];
    int n = end - beg;
    float acc[8];
#pragma unroll
    for (int k = 0; k < 8; ++k) acc[k] = 0.f;
    for (int c0 = 0; c0 < n; c0 += 64) {
        int m = min(64, n - c0);
        int se = (lane < m) ? elist[beg + c0 + lane] : 0;
        int iters = (m + RPI - 1) / RPI;
#pragma unroll 4
        for (int i = 0; i < iters; ++i) {
            int j = i * RPI + r;
            int s = __shfl(se, j);
            if (j < m) {
                f16x8 v = *(const f16x8*)(feat + (size_t)s * W + c * 8);
#pragma unroll
                for (int k = 0; k < 8; ++k) acc[k] += (float)v[k];
            }
        }
    }
#pragma unroll
    for (int k = 0; k < 8; ++k) {
#pragma unroll
        for (int off = SEGS; off < 64; off <<= 1)
            acc[k] += __shfl_xor(acc[k], off);
    }
    if (r == 0) {
        float inv = 1.0f / fmaxf((float)n, 1.0f);
        f16x8 o;
#pragma unroll
        for (int k = 0; k < 8; ++k) o[k] = (_Float16)(acc[k] * inv);
        *(f16x8*)(outp + (size_t)node * W + c * 8) = o;
    }
}

// ---------------- dense SAGE layer 1 via MFMA ----------------
__global__ __launch_bounds__(256) void dense1_kernel(
    const _Float16* __restrict__ A1, const _Float16* __restrict__ A2,
    const _Float16* __restrict__ W1, const _Float16* __restrict__ W2,
    const float* __restrict__ lb,
    const float* __restrict__ bng, const float* __restrict__ bnb,
    const float* __restrict__ bnm, const float* __restrict__ bnv,
    _Float16* __restrict__ out) {
    const int t = threadIdx.x;
    const int w = t >> 6, lane = t & 63;
    const int lrow = lane & 15, lq = lane >> 4;
    const int row0 = blockIdx.x * 64 + w * 16;
    const int ld = min(row0 + lrow, Nn - 1);

    f16x8 a1[4], a2[4];
#pragma unroll
    for (int i = 0; i < 4; ++i) {
        a1[i] = *(const f16x8*)(A1 + (size_t)ld * 128 + i * 32 + lq * 8);
        a2[i] = *(const f16x8*)(A2 + (size_t)ld * 128 + i * 32 + lq * 8);
    }
#pragma unroll
    for (int nt = 0; nt < 8; ++nt) {
        const _Float16* w1r = W1 + (size_t)(nt * 16 + lrow) * 128;
        const _Float16* w2r = W2 + (size_t)(nt * 16 + lrow) * 128;
        f32x4 c = {0.f, 0.f, 0.f, 0.f};
#pragma unroll
        for (int i = 0; i < 4; ++i) {
            c = __builtin_amdgcn_mfma_f32_16x16x32_f16(a1[i], *(const f16x8*)(w1r + i * 32 + lq * 8), c, 0, 0, 0);
            c = __builtin_amdgcn_mfma_f32_16x16x32_f16(a2[i], *(const f16x8*)(w2r + i * 32 + lq * 8), c, 0, 0, 0);
        }
        int cc = nt * 16 + lrow;
        float s = bng[cc] * rsqrtf(bnv[cc] + EPSf);
        float h = (lb[cc] - bnm[cc]) * s + bnb[cc];
#pragma unroll
        for (int r = 0; r < 4; ++r) {
            int gr = row0 + lq * 4 + r;
            if (gr < Nn)
                out[(size_t)gr * 128 + cc] = (_Float16)fmaxf(c[r] * s + h, 0.f);
        }
    }
}

// ---------------- y = h @ W2l^T ----------------
__global__ __launch_bounds__(256) void gemmY_kernel(
    const _Float16* __restrict__ A, const _Float16* __restrict__ W,
    _Float16* __restrict__ out) {
    const int t = threadIdx.x;
    const int w = t >> 6, lane = t & 63;
    const int lrow = lane & 15, lq = lane >> 4;
    const int row0 = blockIdx.x * 64 + w * 16;
    const int ld = min(row0 + lrow, Nn - 1);
    f16x8 a[4];
#pragma unroll
    for (int i = 0; i < 4; ++i)
        a[i] = *(const f16x8*)(A + (size_t)ld * 128 + i * 32 + lq * 8);
#pragma unroll
    for (int nt = 0; nt < 4; ++nt) {
        const _Float16* wr = W + (size_t)(nt * 16 + lrow) * 128;
        f32x4 c = {0.f, 0.f, 0.f, 0.f};
#pragma unroll
        for (int i = 0; i < 4; ++i)
            c = __builtin_amdgcn_mfma_f32_16x16x32_f16(a[i], *(const f16x8*)(wr + i * 32 + lq * 8), c, 0, 0, 0);
        int cc = nt * 16 + lrow;
#pragma unroll
        for (int r = 0; r < 4; ++r) {
            int gr = row0 + lq * 4 + r;
            if (gr < Nn) out[(size_t)gr * 64 + cc] = (_Float16)c[r];
        }
    }
}

// ---------------- z = aggY + h @ W2r^T + lb ----------------
__global__ __launch_bounds__(256) void dense2b_kernel(
    const _Float16* __restrict__ aggY, const _Float16* __restrict__ A2,
    const _Float16* __restrict__ W2, const float* __restrict__ lb,
    _Float16* __restrict__ out) {
    const int t = threadIdx.x;
    const int w = t >> 6, lane = t & 63;
    const int lrow = lane & 15, lq = lane >> 4;
    const int row0 = blockIdx.x * 64 + w * 16;
    const int ld = min(row0 + lrow, Nn - 1);
    f16x8 a[4];
#pragma unroll
    for (int i = 0; i < 4; ++i)
        a[i] = *(const f16x8*)(A2 + (size_t)ld * 128 + i * 32 + lq * 8);
#pragma unroll
    for (int nt = 0; nt < 4; ++nt) {
        const _Float16* wr = W2 + (size_t)(nt * 16 + lrow) * 128;
        f32x4 c = {0.f, 0.f, 0.f, 0.f};
#pragma unroll
        for (int i = 0; i < 4; ++i)
            c = __builtin_amdgcn_mfma_f32_16x16x32_f16(a[i], *(const f16x8*)(wr + i * 32 + lq * 8), c, 0, 0, 0);
        int cc = nt * 16 + lrow;
        float b = lb[cc];
#pragma unroll
        for (int r = 0; r < 4; ++r) {
            int gr = row0 + lq * 4 + r;
            if (gr < Nn) {
                float g = (float)aggY[(size_t)gr * 64 + cc];
                out[(size_t)gr * 64 + cc] = (_Float16)(c[r] + g + b);
            }
        }
    }
}

// ---------------- edge-feature MLP: e2 = (relu(bn(ef@We1^T)))@We2^T + eb2 ----
__global__ __launch_bounds__(256) void emlp_kernel(
    const float* __restrict__ ef,
    const _Float16* __restrict__ w16,
    const float* __restrict__ bnA,
    _Float16* __restrict__ e2out) {
    __shared__ __align__(16) _Float16 E1[64 * 72];
    const int t = threadIdx.x;
    const int lane = t & 63, w = t >> 6;
    const int lrow = lane & 15, lq = lane >> 4;
    const int e0 = blockIdx.x * 64 + w * 16;
    const int erow = w * 16 + lrow;

    const float* src = ef + (size_t)(e0 + lrow) * 32 + lq * 8;
    float4 f0 = ld4(src), f1 = ld4(src + 4);
    f16x8 bf = {(_Float16)f0.x, (_Float16)f0.y, (_Float16)f0.z, (_Float16)f0.w,
                (_Float16)f1.x, (_Float16)f1.y, (_Float16)f1.z, (_Float16)f1.w};

#pragma unroll
    for (int nt = 0; nt < 4; ++nt) {
        f16x8 wf = *(const f16x8*)(w16 + oWe1 + (nt * 16 + lrow) * 32 + lq * 8);
        f32x4 c = {0.f, 0.f, 0.f, 0.f};
        c = __builtin_amdgcn_mfma_f32_16x16x32_f16(wf, bf, c, 0, 0, 0);
        int cb = nt * 16 + lq * 4;
        float4 s = *(const float4*)(bnA + cb);
        float4 h = *(const float4*)(bnA + 64 + cb);
        f16x4 o;
        o[0] = (_Float16)fmaxf(c[0] * s.x + h.x, 0.f);
        o[1] = (_Float16)fmaxf(c[1] * s.y + h.y, 0.f);
        o[2] = (_Float16)fmaxf(c[2] * s.z + h.z, 0.f);
        o[3] = (_Float16)fmaxf(c[3] * s.w + h.w, 0.f);
        *(f16x4*)(E1 + erow * 72 + cb) = o;
    }
    f16x8 a0 = *(const f16x8*)(E1 + erow * 72 + lq * 8);
    f16x8 a1 = *(const f16x8*)(E1 + erow * 72 + 32 + lq * 8);
#pragma unroll
    for (int nt = 0; nt < 2; ++nt) {
        f16x8 b0 = *(const f16x8*)(w16 + oWe2 + (nt * 16 + lrow) * 64 + lq * 8);
        f16x8 b1 = *(const f16x8*)(w16 + oWe2 + (nt * 16 + lrow) * 64 + 32 + lq * 8);
        f32x4 c = {0.f, 0.f, 0.f, 0.f};
        c = __builtin_amdgcn_mfma_f32_16x16x32_f16(b0, a0, c, 0, 0, 0);
        c = __builtin_amdgcn_mfma_f32_16x16x32_f16(b1, a1, c, 0, 0, 0);
        int cb = nt * 16 + lq * 4;
        float4 bias = *(const float4*)(bnA + 512 + cb);
        f16x4 o;
        o[0] = (_Float16)(c[0] + bias.x);
        o[1] = (_Float16)(c[1] + bias.y);
        o[2] = (_Float16)(c[2] + bias.z);
        o[3] = (_Float16)(c[3] + bias.w);
        *(f16x4*)(e2out + (size_t)(e0 + lrow) * 32 + cb) = o;
    }
}

// ---------------- fused predictor: 1024 thr = 16 waves/CU, direct frag gathers ----
// (R4-proven configuration: full-width ZU, F/G data prefetch, 1 block/CU.)
#define EPB 256
#define NT  ((Pp + EPB - 1) / EPB)     // 3907
#define EGRID 256

#define oL_W1a 0        // [128][72]  18432
#define oL_W1b 18432    // [128][72]  18432
#define oL_W1c 36864    // [128][40]  10240
#define oL_Wp2 47104    // [64][136]  17408
#define oL_BN  64512    // 448 f32    1792
#define oL_ZU  66304    // [256][136] 69632
#define SMEM_BYTES 135936

__global__ __launch_bounds__(1024, 4) void edge_kernel(
    const int* __restrict__ pe,
    const _Float16* __restrict__ e2,     // [P,32]
    const _Float16* __restrict__ z,      // [N,64]
    const _Float16* __restrict__ w16,
    const float* __restrict__ bnA,
    const float* __restrict__ pb3,
    float* __restrict__ out) {
    __shared__ __align__(16) unsigned char smem[SMEM_BYTES];
    _Float16* LW1a = (_Float16*)(smem + oL_W1a);
    _Float16* LW1b = (_Float16*)(smem + oL_W1b);
    _Float16* LW1c = (_Float16*)(smem + oL_W1c);
    _Float16* LWp2 = (_Float16*)(smem + oL_Wp2);
    float*    LBN  = (float*)(smem + oL_BN);
    _Float16* ZU   = (_Float16*)(smem + oL_ZU);

    const float* bn2s = LBN;        const float* bn2h = LBN + 128;
    const float* bn3s = LBN + 256;  const float* bn3h = LBN + 320;
    const float* wp3g = LBN + 384;

    const int t = threadIdx.x;
    const int lane = t & 63;
    const int w = t >> 6;          // 0..15
    const int m0 = w * 16;
    const int lrow = lane & 15;
    const int lq = lane >> 4;
    const float pb3v = pb3[0];

    auto load_idx = [&](int tl, int& ia, int& ib) {
        int e = min(tl * EPB + m0 + lrow, Pp - 1);
        ia = pe[e];
        ib = pe[Pp + e];
    };
    auto gather = [&](int tl, int ia, int ib, f16x8* F) {
        F[0] = *(const f16x8*)(z + (size_t)ia * 64 + lq * 8);
        F[1] = *(const f16x8*)(z + (size_t)ia * 64 + 32 + lq * 8);
        F[2] = *(const f16x8*)(z + (size_t)ib * 64 + lq * 8);
        F[3] = *(const f16x8*)(z + (size_t)ib * 64 + 32 + lq * 8);
        int e = min(tl * EPB + m0 + lrow, Pp - 1);
        F[4] = *(const f16x8*)(e2 + (size_t)e * 32 + lq * 8);
    };

    int tile = blockIdx.x;
    int ia1, ib1;
    {
        int ia0, ib0;
        load_idx(tile, ia0, ib0);
        load_idx(tile + EGRID, ia1, ib1);
        f16x8 F[5];
        gather(tile, ia0, ib0, F);

        { int r = t >> 3, s = t & 7;
          *(f16x8*)(LW1a + r * 72 + s * 8) = *(const f16x8*)(w16 + oW1a + r * 64 + s * 8);
          *(f16x8*)(LW1b + r * 72 + s * 8) = *(const f16x8*)(w16 + oW1b + r * 64 + s * 8); }
        if (t < 512) { int r = t >> 2, s = t & 3;
          *(f16x8*)(LW1c + r * 40 + s * 8) = *(const f16x8*)(w16 + oW1c + r * 32 + s * 8); }
        { int r = t >> 4, s = t & 15;
          *(f16x8*)(LWp2 + r * 136 + s * 8) = *(const f16x8*)(w16 + oWp2 + r * 128 + s * 8); }
        if (t < 384) LBN[t] = bnA[128 + t];
        else if (t < 448) LBN[t] = bnA[544 + (t - 384)];
        __syncthreads();

        const int erow = m0 + lrow;
        const int zr = erow * 136;
        for (; tile < NT; tile += EGRID) {
            f16x8 G[5];
            gather(tile + EGRID, ia1, ib1, G);
            int ia2, ib2;
            load_idx(tile + 2 * EGRID, ia2, ib2);

            const bool act = (tile * EPB + m0) < Pp;
            if (act) {
                __builtin_amdgcn_s_setprio(1);
#pragma unroll
                for (int nt = 0; nt < 8; ++nt) {
                    const _Float16* wa = LW1a + (nt * 16 + lrow) * 72;
                    const _Float16* wb = LW1b + (nt * 16 + lrow) * 72;
                    const _Float16* wc = LW1c + (nt * 16 + lrow) * 40;
                    f32x4 c = {0.f, 0.f, 0.f, 0.f};
                    c = __builtin_amdgcn_mfma_f32_16x16x32_f16(*(const f16x8*)(wa + lq * 8),      F[0], c, 0, 0, 0);
                    c = __builtin_amdgcn_mfma_f32_16x16x32_f16(*(const f16x8*)(wa + 32 + lq * 8), F[1], c, 0, 0, 0);
                    c = __builtin_amdgcn_mfma_f32_16x16x32_f16(*(const f16x8*)(wb + lq * 8),      F[2], c, 0, 0, 0);
                    c = __builtin_amdgcn_mfma_f32_16x16x32_f16(*(const f16x8*)(wb + 32 + lq * 8), F[3], c, 0, 0, 0);
                    c = __builtin_amdgcn_mfma_f32_16x16x32_f16(*(const f16x8*)(wc + lq * 8),      F[4], c, 0, 0, 0);
                    int cb = nt * 16 + lq * 4;
                    float4 s = *(const float4*)(bn2s + cb);
                    float4 h = *(const float4*)(bn2h + cb);
                    f16x4 o;
                    o[0] = (_Float16)fmaxf(c[0] * s.x + h.x, 0.f);
                    o[1] = (_Float16)fmaxf(c[1] * s.y + h.y, 0.f);
                    o[2] = (_Float16)fmaxf(c[2] * s.z + h.z, 0.f);
                    o[3] = (_Float16)fmaxf(c[3] * s.w + h.w, 0.f);
                    *(f16x4*)(ZU + zr + cb) = o;
                }
                __builtin_amdgcn_s_setprio(0);
                {
                    f16x8 a0 = *(const f16x8*)(ZU + zr + 0  + lq * 8);
                    f16x8 a1 = *(const f16x8*)(ZU + zr + 32 + lq * 8);
                    f16x8 a2 = *(const f16x8*)(ZU + zr + 64 + lq * 8);
                    f16x8 a3 = *(const f16x8*)(ZU + zr + 96 + lq * 8);
                    float acc = 0.f;
                    __builtin_amdgcn_s_setprio(1);
#pragma unroll
                    for (int nt = 0; nt < 4; ++nt) {
                        const _Float16* wr = LWp2 + (nt * 16 + lrow) * 136 + lq * 8;
                        f32x4 c = {0.f, 0.f, 0.f, 0.f};
                        c = __builtin_amdgcn_mfma_f32_16x16x32_f16(*(const f16x8*)(wr + 0),  a0, c, 0, 0, 0);
                        c = __builtin_amdgcn_mfma_f32_16x16x32_f16(*(const f16x8*)(wr + 32), a1, c, 0, 0, 0);
                        c = __builtin_amdgcn_mfma_f32_16x16x32_f16(*(const f16x8*)(wr + 64), a2, c, 0, 0, 0);
                        c = __builtin_amdgcn_mfma_f32_16x16x32_f16(*(const f16x8*)(wr + 96), a3, c, 0, 0, 0);
                        int cb = nt * 16 + lq * 4;
                        float4 s  = *(const float4*)(bn3s + cb);
                        float4 h  = *(const float4*)(bn3h + cb);
                        float4 w3 = *(const float4*)(wp3g + cb);
                        acc += fmaxf(c[0] * s.x + h.x, 0.f) * w3.x;
                        acc += fmaxf(c[1] * s.y + h.y, 0.f) * w3.y;
                        acc += fmaxf(c[2] * s.z + h.z, 0.f) * w3.z;
                        acc += fmaxf(c[3] * s.w + h.w, 0.f) * w3.w;
                    }
                    __builtin_amdgcn_s_setprio(0);
                    acc += __shfl_xor(acc, 16);
                    acc += __shfl_xor(acc, 32);
                    if (lane < 16) out[tile * EPB + m0 + lane] = acc + pb3v;
                }
            }
#pragma unroll
            for (int i = 0; i < 5; ++i) F[i] = G[i];
            ia1 = ia2; ib1 = ib2;
        }
    }
}

// ---------------- launch ----------------
extern "C" void kernel_launch(void* const* d_in, const int* in_sizes, int n_in,
                              void* d_out, int out_size, void* d_ws, size_t ws_size,
                              hipStream_t stream) {
    const float* x    = (const float*)d_in[0];
    const int*   eidx = (const int*)d_in[1];
    const int*   pe   = (const int*)d_in[2];
    const float* ef   = (const float*)d_in[3];
    const float* s1Wl = (const float*)d_in[4];
    const float* s1bl = (const float*)d_in[5];
    const float* s1Wr = (const float*)d_in[6];
    const float* bn1g = (const float*)d_in[7];
    const float* bn1b = (const float*)d_in[8];
    const float* bn1m = (const float*)d_in[9];
    const float* bn1v = (const float*)d_in[10];
    const float* s2Wl = (const float*)d_in[11];
    const float* s2bl = (const float*)d_in[12];
    const float* s2Wr = (const float*)d_in[13];
    const float* eW1  = (const float*)d_in[14];
    const float* eb1  = (const float*)d_in[15];
    const float* ebng = (const float*)d_in[16];
    const float* ebnb = (const float*)d_in[17];
    const float* ebnm = (const float*)d_in[18];
    const float* ebnv = (const float*)d_in[19];
    const float* eW2  = (const float*)d_in[20];
    const float* eb2  = (const float*)d_in[21];
    const float* pW1  = (const float*)d_in[22];
    const float* pb1  = (const float*)d_in[23];
    const float* p1g  = (const float*)d_in[24];
    const float* p1b  = (const float*)d_in[25];
    const float* p1m  = (const float*)d_in[26];
    const float* p1v  = (const float*)d_in[27];
    const float* pW2  = (const float*)d_in[28];
    const float* pb2  = (const float*)d_in[29];
    const float* p2g  = (const float*)d_in[30];
    const float* p2b  = (const float*)d_in[31];
    const float* p2m  = (const float*)d_in[32];
    const float* p2v  = (const float*)d_in[33];
    const float* pW3  = (const float*)d_in[34];
    const float* pb3  = (const float*)d_in[35];
    float* out = (float*)d_out;

    char* wk = (char*)d_ws;
    auto carve = [&](size_t bytes) {
        char* p = wk;
        wk += (bytes + 255) & ~(size_t)255;
        return p;
    };
    unsigned*  deg    = (unsigned*)carve((size_t)Nn * 4);
    unsigned*  gcur   = (unsigned*)carve((size_t)256 * 4);
    int*       rowptr = (int*)carve((size_t)(Nn + 1) * 4);
    int*       elist  = (int*)carve((size_t)Ee * 4);
    unsigned*  escan  = (unsigned*)carve((size_t)Nn * 4);
    unsigned*  bsum   = (unsigned*)carve(128 * 4);
    unsigned*  boff   = (unsigned*)carve(128 * 4);
    _Float16*  w16    = (_Float16*)carve((size_t)W16_TOTAL * 2);
    float*     bnA    = (float*)carve((size_t)BN_TOTAL * 4);
    _Float16*  bufX   = (_Float16*)carve((size_t)Nn * 128 * 2);  // x16; later y|z
    _Float16*  bufA   = (_Float16*)carve((size_t)Nn * 128 * 2);  // agg1 out; later aggY
    _Float16*  bufH   = (_Float16*)carve((size_t)Nn * 128 * 2);  // h (dead during CSR build)
    _Float16*  e2buf  = (_Float16*)carve((size_t)Pp * 32 * 2);   // edge MLP out
    _Float16*  bufY   = bufX;
    _Float16*  bufZ   = bufX + (size_t)Nn * 64;
    _Float16*  bufAy  = bufA;
    unsigned*  stage  = (unsigned*)bufH;   // alias: 7.2 MB <= 25.6 MB, dead here

    const int* e_src = eidx;
    const int* e_dst = eidx + Ee;
    const int SBLK = (Nn + 1023) / 1024;   // 98

    hipMemsetAsync(gcur, 0, 256 * 4, stream);

    prep_kernel<<<800, 256, 0, stream>>>(x, s1Wl, s1Wr, s2Wl, s2Wr, pW1, eW1, eW2, pW2,
                                         eb1, ebng, ebnb, ebnm, ebnv, eb2,
                                         pb1, p1g, p1b, p1m, p1v,
                                         pb2, p2g, p2b, p2m, p2v, pW3,
                                         w16, bnA, bufX);
    // edge-feature MLP (independent of graph; streaming)
    emlp_kernel<<<Pp / 64, 256, 0, stream>>>(ef, w16, bnA, e2buf);

    // CSR build: block-local multisplit (no per-edge global atomics)
    bucketA_kernel<<<NCHUNK, 256, 0, stream>>>(e_src, e_dst, stage, gcur);
    countC_kernel<<<NB2, 256, 0, stream>>>(stage, gcur, deg);
    scanA_kernel<<<SBLK, 1024, 0, stream>>>(deg, escan, bsum);
    scanB_kernel<<<1, 128, 0, stream>>>(bsum, boff, SBLK);
    scanC_kernel<<<SBLK, 1024, 0, stream>>>(escan, boff, rowptr);
    scatterE_kernel<<<NB2, 256, 0, stream>>>(stage, gcur, rowptr, elist);

    // SAGE layer 1
    aggregate16_kernel<128><<<Nn / 4, 256, 0, stream>>>(bufX, rowptr, elist, bufA);
    dense1_kernel<<<(Nn + 63) / 64, 256, 0, stream>>>(
        bufA, bufX, w16 + oW1l, w16 + oW1r, s1bl, bn1g, bn1b, bn1m, bn1v, bufH);

    // SAGE layer 2 (linear commutes with mean)
    gemmY_kernel<<<(Nn + 63) / 64, 256, 0, stream>>>(bufH, w16 + oW2l, bufY);
    aggregate16_kernel<64><<<Nn / 4, 256, 0, stream>>>(bufY, rowptr, elist, bufAy);
    dense2b_kernel<<<(Nn + 63) / 64, 256, 0, stream>>>(
        bufAy, bufH, w16 + oW2r, s2bl, bufZ);

    // fused per-edge predictor (R4 config: 16 waves/CU, direct fragment gathers)
    edge_kernel<<<EGRID, 1024, 0, stream>>>(pe, e2buf, bufZ, w16, bnA, pb3, out);
}